// Round 1
// baseline (183.070 us; speedup 1.0000x reference)
//
#include <hip/hip_runtime.h>
#include <cstdint>
#include <cstddef>

#define DEV static __device__ __forceinline__

typedef __bf16 bf16x8 __attribute__((ext_vector_type(8)));
typedef __bf16 bf16x4 __attribute__((ext_vector_type(4)));
typedef float  f32x4  __attribute__((ext_vector_type(4)));
typedef unsigned short us4 __attribute__((ext_vector_type(4)));
typedef unsigned short us8 __attribute__((ext_vector_type(8)));

DEV unsigned short f2bf(float f) {
  unsigned u = __float_as_uint(f);
  u += 0x7FFFu + ((u >> 16) & 1u);          // round-to-nearest-even
  return (unsigned short)(u >> 16);
}
DEV float bf2f(unsigned short s) { return __uint_as_float(((unsigned)s) << 16); }

// fixed problem dims
constexpr int   Bn = 4, Nn = 4096, Cn = 256, HEADSn = 8, DHn = 32, NKn = 1024;
constexpr float SCALEc = 0.17677669529663689f;   // 1/sqrt(32)
constexpr float L2E    = 1.4426950408889634f;

// ---------------- f32 -> bf16 convert (4 elems/thread) ----------------
__global__ void k_f32_to_bf16(const float* __restrict__ src,
                              unsigned short* __restrict__ dst, int n4) {
  int i = blockIdx.x * blockDim.x + threadIdx.x;
  if (i < n4) {
    f32x4 v = *(const f32x4*)(src + 4 * (size_t)i);
    us4 o;
    o[0] = f2bf(v[0]); o[1] = f2bf(v[1]); o[2] = f2bf(v[2]); o[3] = f2bf(v[3]);
    *(us4*)(dst + 4 * (size_t)i) = o;
  }
}

// ---------------- depthwise 2x2 stride-2 conv + BatchNorm(eval) -> xk bf16 ----------------
__global__ void k_conv_bn(const float* __restrict__ x,
                          const float* __restrict__ srw, const float* __restrict__ srb,
                          const float* __restrict__ bng, const float* __restrict__ bnb,
                          const float* __restrict__ bnm, const float* __restrict__ bnv,
                          unsigned short* __restrict__ xk) {
  const int m = blockIdx.x;           // 0..1023  (i*32+j)
  const int b = blockIdx.y;           // 0..3
  const int c = threadIdx.x;          // 0..255
  const int i = m >> 5, j = m & 31;
  const int n00 = (2 * i) * 64 + 2 * j;
  const size_t base = ((size_t)b * Nn) * Cn + c;
  float w0 = srw[c * 4 + 0], w1 = srw[c * 4 + 1], w2 = srw[c * 4 + 2], w3 = srw[c * 4 + 3];
  float acc = x[base + (size_t)n00 * Cn] * w0
            + x[base + (size_t)(n00 + 1) * Cn] * w1
            + x[base + (size_t)(n00 + 64) * Cn] * w2
            + x[base + (size_t)(n00 + 65) * Cn] * w3
            + srb[c];
  float inv_std = bng[c] * rsqrtf(bnv[c] + 1e-5f);
  acc = (acc - bnm[c]) * inv_std + bnb[c];
  xk[((size_t)b * NKn + m) * Cn + c] = f2bf(acc);
}

// ---------------- bf16 MFMA GEMM: out[m,o] = sum_k A[m,k] * W[o,k] ----------------
// MODE 0: bf16 out [M,256];  MODE 1: bf16 transposed v_t[b,h,dv,kv];  MODE 2: f32 out + bias
template <int MODE>
__global__ __launch_bounds__(256) void k_gemm(const unsigned short* __restrict__ A,
                                              const unsigned short* __restrict__ W,
                                              void* __restrict__ outp,
                                              const float* __restrict__ bias) {
  const int lane = threadIdx.x & 63, wid = threadIdx.x >> 6;
  const int g = lane >> 4, c = lane & 15;
  const int m0 = blockIdx.x * 16, o0 = wid * 64;
  f32x4 acc[4] = {};
  const unsigned short* ap = A + (size_t)(m0 + c) * Cn + 8 * g;
#pragma unroll
  for (int ks = 0; ks < 8; ++ks) {
    bf16x8 af = *(const bf16x8*)(ap + ks * 32);
#pragma unroll
    for (int t = 0; t < 4; ++t) {
      bf16x8 wf = *(const bf16x8*)(W + (size_t)(o0 + 16 * t + c) * Cn + ks * 32 + 8 * g);
      acc[t] = __builtin_amdgcn_mfma_f32_16x16x32_bf16(af, wf, acc[t], 0, 0, 0);
    }
  }
  if (MODE == 0) {
    unsigned short* ob = (unsigned short*)outp;
#pragma unroll
    for (int t = 0; t < 4; ++t)
#pragma unroll
      for (int r = 0; r < 4; ++r)
        ob[(size_t)(m0 + 4 * g + r) * Cn + o0 + 16 * t + c] = f2bf(acc[t][r]);
  } else if (MODE == 1) {
    unsigned short* vt = (unsigned short*)outp;
    const int bb = m0 >> 10, kv = (m0 & 1023) + 4 * g;
#pragma unroll
    for (int t = 0; t < 4; ++t) {
      const int o = o0 + 16 * t + c;
      us4 pk;
      pk[0] = f2bf(acc[t][0]); pk[1] = f2bf(acc[t][1]);
      pk[2] = f2bf(acc[t][2]); pk[3] = f2bf(acc[t][3]);
      *(us4*)(vt + ((size_t)((bb * 8 + (o >> 5)) * 32 + (o & 31))) * NKn + kv) = pk;
    }
  } else {
    float* of = (float*)outp;
#pragma unroll
    for (int t = 0; t < 4; ++t) {
      const int o = o0 + 16 * t + c;
      const float bv = bias[o];
#pragma unroll
      for (int r = 0; r < 4; ++r)
        of[(size_t)(m0 + 4 * g + r) * Cn + o] = acc[t][r] + bv;
    }
  }
}

// ---------------- fused attention: per block = (64 q rows, head h), wave = batch ----------------
__global__ __launch_bounds__(256) void k_attn(const unsigned short* __restrict__ qb,
                                              const unsigned short* __restrict__ kp,
                                              const unsigned short* __restrict__ vt,
                                              const float* __restrict__ rel,
                                              unsigned short* __restrict__ ob) {
  const int lane = threadIdx.x & 63, bb = threadIdx.x >> 6;  // wave = batch
  const int g = lane >> 4, c = lane & 15;
  const int h = blockIdx.y, q0 = blockIdx.x * 64;

  // Q fragments (B-operand: col = q index), held for the whole kernel
  bf16x8 qf[4];
#pragma unroll
  for (int t = 0; t < 4; ++t)
    qf[t] = *(const bf16x8*)(qb + ((size_t)bb * Nn + q0 + 16 * t + c) * Cn + h * DHn + 8 * g);

  f32x4 acc[4][2] = {};
  float m_s[4], l_s[4];
#pragma unroll
  for (int t = 0; t < 4; ++t) { m_s[t] = -1e30f; l_s[t] = 0.f; }

  const unsigned short* kbase = kp + ((size_t)bb * NKn) * Cn + h * DHn + 8 * g;
  const unsigned short* vbase = vt + ((size_t)(bb * HEADSn + h) * DHn) * NKn;
  const float* rbase = rel + ((size_t)h * Nn + q0) * NKn;

  for (int kv0 = 0; kv0 < NKn; kv0 += 32) {
    // K fragments (A-operand rows = kv)
    bf16x8 kf0 = *(const bf16x8*)(kbase + (size_t)(kv0 + c) * Cn);
    bf16x8 kf1 = *(const bf16x8*)(kbase + (size_t)(kv0 + 16 + c) * Cn);
    // V^T fragments, k-slot bijection k'(g,j) = {4g+j, 16+4g+(j-4)}
    bf16x8 vf[2];
#pragma unroll
    for (int hh = 0; hh < 2; ++hh) {
      const unsigned short* vp = vbase + (size_t)(hh * 16 + c) * NKn + kv0 + 4 * g;
      bf16x4 lo = *(const bf16x4*)(vp);
      bf16x4 hi = *(const bf16x4*)(vp + 16);
      vf[hh] = __builtin_shufflevector(lo, hi, 0, 1, 2, 3, 4, 5, 6, 7);
    }
#pragma unroll
    for (int t = 0; t < 4; ++t) {
      f32x4 zero = {};
      f32x4 s0 = __builtin_amdgcn_mfma_f32_16x16x32_bf16(kf0, qf[t], zero, 0, 0, 0);
      f32x4 s1 = __builtin_amdgcn_mfma_f32_16x16x32_bf16(kf1, qf[t], zero, 0, 0, 0);
      const float* rp = rbase + (size_t)(16 * t + c) * NKn + kv0 + 4 * g;
      f32x4 r0 = *(const f32x4*)rp;
      f32x4 r1 = *(const f32x4*)(rp + 16);
#pragma unroll
      for (int r = 0; r < 4; ++r) {
        s0[r] = s0[r] * SCALEc + r0[r];
        s1[r] = s1[r] * SCALEc + r1[r];
      }
      float mx = fmaxf(fmaxf(fmaxf(s0[0], s0[1]), fmaxf(s0[2], s0[3])),
                       fmaxf(fmaxf(s1[0], s1[1]), fmaxf(s1[2], s1[3])));
      mx = fmaxf(mx, __shfl_xor(mx, 16));
      mx = fmaxf(mx, __shfl_xor(mx, 32));
      const float mn = fmaxf(m_s[t], mx);
      const float al = exp2f((m_s[t] - mn) * L2E);
      m_s[t] = mn;
      float p0[4], p1[4], sm = 0.f;
#pragma unroll
      for (int r = 0; r < 4; ++r) {
        p0[r] = exp2f((s0[r] - mn) * L2E);
        p1[r] = exp2f((s1[r] - mn) * L2E);
        sm += p0[r] + p1[r];
      }
      sm += __shfl_xor(sm, 16);
      sm += __shfl_xor(sm, 32);
      l_s[t] = l_s[t] * al + sm;
      us8 pv;
      pv[0] = f2bf(p0[0]); pv[1] = f2bf(p0[1]); pv[2] = f2bf(p0[2]); pv[3] = f2bf(p0[3]);
      pv[4] = f2bf(p1[0]); pv[5] = f2bf(p1[1]); pv[6] = f2bf(p1[2]); pv[7] = f2bf(p1[3]);
      bf16x8 pf = __builtin_bit_cast(bf16x8, pv);
#pragma unroll
      for (int hh = 0; hh < 2; ++hh) {
        acc[t][hh] *= al;
        acc[t][hh] = __builtin_amdgcn_mfma_f32_16x16x32_bf16(vf[hh], pf, acc[t][hh], 0, 0, 0);
      }
    }
  }
  // epilogue: divide by l, write attn output bf16 [b, n, h*32 + dv]
#pragma unroll
  for (int t = 0; t < 4; ++t) {
    const float inv = 1.0f / l_s[t];
#pragma unroll
    for (int hh = 0; hh < 2; ++hh) {
      us4 pk;
      pk[0] = f2bf(acc[t][hh][0] * inv);
      pk[1] = f2bf(acc[t][hh][1] * inv);
      pk[2] = f2bf(acc[t][hh][2] * inv);
      pk[3] = f2bf(acc[t][hh][3] * inv);
      *(us4*)(ob + ((size_t)bb * Nn + q0 + 16 * t + c) * Cn + h * DHn + hh * 16 + 4 * g) = pk;
    }
  }
}

extern "C" void kernel_launch(void* const* d_in, const int* in_sizes, int n_in,
                              void* d_out, int out_size, void* d_ws, size_t ws_size,
                              hipStream_t stream) {
  const float* x   = (const float*)d_in[0];
  const float* rel = (const float*)d_in[3];
  const float* qw  = (const float*)d_in[4];
  const float* kw  = (const float*)d_in[5];
  const float* vw  = (const float*)d_in[6];
  const float* pw  = (const float*)d_in[7];
  const float* pb  = (const float*)d_in[8];
  const float* srw = (const float*)d_in[9];
  const float* srb = (const float*)d_in[10];
  const float* bng = (const float*)d_in[11];
  const float* bnb = (const float*)d_in[12];
  const float* bnm = (const float*)d_in[13];
  const float* bnv = (const float*)d_in[14];

  char* ws = (char*)d_ws;
  unsigned short* x_bf  = (unsigned short*)(ws + 0);          // 16384x256 bf16 (8 MB)
  unsigned short* q_bf  = (unsigned short*)(ws + 8388608);    // 16384x256 bf16 (8 MB)
  unsigned short* xk_bf = (unsigned short*)(ws + 16777216);   // 4096x256  bf16 (2 MB)
  unsigned short* k_bf  = (unsigned short*)(ws + 18874368);   // 4096x256  bf16 (2 MB)
  unsigned short* v_t   = (unsigned short*)(ws + 20971520);   // [4,8,32,1024] bf16 (2 MB)
  unsigned short* a_bf  = (unsigned short*)(ws + 23068672);   // 16384x256 bf16 (8 MB)
  unsigned short* w_q   = (unsigned short*)(ws + 31457280);
  unsigned short* w_k   = (unsigned short*)(ws + 31457280 + 131072);
  unsigned short* w_v   = (unsigned short*)(ws + 31457280 + 262144);
  unsigned short* w_p   = (unsigned short*)(ws + 31457280 + 393216);

  // convert inputs to bf16
  k_f32_to_bf16<<<4096, 256, 0, stream>>>(x, x_bf, 1048576);
  k_f32_to_bf16<<<64, 256, 0, stream>>>(qw, w_q, 16384);
  k_f32_to_bf16<<<64, 256, 0, stream>>>(kw, w_k, 16384);
  k_f32_to_bf16<<<64, 256, 0, stream>>>(vw, w_v, 16384);
  k_f32_to_bf16<<<64, 256, 0, stream>>>(pw, w_p, 16384);

  // spatial reduction + BN
  k_conv_bn<<<dim3(1024, 4), 256, 0, stream>>>(x, srw, srb, bng, bnb, bnm, bnv, xk_bf);

  // projections
  k_gemm<0><<<1024, 256, 0, stream>>>(x_bf, w_q, (void*)q_bf, nullptr);  // Q: 16384x256
  k_gemm<0><<<256, 256, 0, stream>>>(xk_bf, w_k, (void*)k_bf, nullptr);  // K: 4096x256
  k_gemm<1><<<256, 256, 0, stream>>>(xk_bf, w_v, (void*)v_t, nullptr);   // V (transposed out)

  // fused attention
  k_attn<<<dim3(64, 8), 256, 0, stream>>>(q_bf, k_bf, v_t, rel, a_bf);

  // output projection (f32 + bias) -> d_out
  k_gemm<2><<<1024, 256, 0, stream>>>(a_bf, w_p, d_out, pb);
}